// Round 5
// baseline (333.379 us; speedup 1.0000x reference)
//
#include <hip/hip_runtime.h>
#include <hip/hip_bf16.h>
#include <math.h>

// Problem constants (fixed by setup_inputs)
#define BB 16
#define TT 8192
#define DD 256
#define MAXSEG 4096   // max possible segments per row (alternating pattern)
#define RPB 8         // tile granularity (fill tiles; grid y)
#define LROWS 32      // segment rows per LEADER block (amortizes Wt stream 4x)
#define LN_EPS 1e-5f

typedef float vfloat4 __attribute__((ext_vector_type(4)));  // nontemporal-safe

// ---------------------------------------------------------------------------
// Setup kernel (merged): blocks [0,BB) run the per-batch-row segment scan;
// blocks [BB, BB+64) transpose W (4 rows each); block BB+64 computes
// LN(b_proj) with a single wave. 1024 threads each.
__global__ __launch_bounds__(1024) void setup_kernel(
    const int* __restrict__ ids, const float* __restrict__ W,
    const float* __restrict__ bp, const float* __restrict__ gamma,
    const float* __restrict__ beta, int* __restrict__ counts,
    int* __restrict__ seg_start, int* __restrict__ nseg_g,
    float* __restrict__ mask_out, float* __restrict__ Wt,
    float* __restrict__ ln_empty) {
    __shared__ int wtot_s[16];
    __shared__ int wtot_n[16];
    __shared__ int segs[MAXSEG];
    __shared__ int pvals[MAXSEG];

    int tid = threadIdx.x;
    int lane = tid & 63;
    int wv = tid >> 6;

    if (blockIdx.x >= BB) {
        int bi = blockIdx.x - BB;
        if (bi < 64) {  // transpose: 4 d-rows per block
            int d = bi * 4 + (tid >> 8);
            int e = tid & 255;
            Wt[d * DD + e] = W[e * DD + d];
        } else if (wv == 0) {  // LN of b_proj, one wave
            int e0 = lane * 4;
            float4 v = *(const float4*)(bp + e0);
            float s = v.x + v.y + v.z + v.w;
            float sq = v.x * v.x + v.y * v.y + v.z * v.z + v.w * v.w;
#pragma unroll
            for (int o = 32; o > 0; o >>= 1) {
                s += __shfl_down(s, o);
                sq += __shfl_down(sq, o);
            }
            s = __shfl(s, 0);
            sq = __shfl(sq, 0);
            float mu = s * (1.f / (float)DD);
            float var = sq * (1.f / (float)DD) - mu * mu;
            float rs = rsqrtf(fmaxf(var, 0.f) + LN_EPS);
            float4 ge = *(const float4*)(gamma + e0);
            float4 be = *(const float4*)(beta + e0);
            float4 o4;
            o4.x = (v.x - mu) * rs * ge.x + be.x;
            o4.y = (v.y - mu) * rs * ge.y + be.y;
            o4.z = (v.z - mu) * rs * ge.z + be.z;
            o4.w = (v.w - mu) * rs * ge.w + be.w;
            *(float4*)(ln_empty + e0) = o4;
        }
        return;
    }

    // ---- segment scan, one block per batch row
    const int TPT = 8;  // tokens per thread
    int b = blockIdx.x;
    const int* row = ids + b * TT;
    int t0 = tid * TPT;

    int4 q0 = ((const int4*)(row + t0))[0];
    int4 q1 = ((const int4*)(row + t0))[1];
    int v[TPT] = {q0.x, q0.y, q0.z, q0.w, q1.x, q1.y, q1.z, q1.w};
    int prev = (tid == 0) ? 0 : row[t0 - 1];  // 0 == boundary

    bool nb[TPT], st[TPT];
    int cstart = 0, cnon = 0;
#pragma unroll
    for (int j = 0; j < TPT; ++j) {
        nb[j] = (v[j] != 0);
        int pv = (j == 0) ? prev : v[j - 1];
        st[j] = nb[j] && (pv == 0);
        cstart += st[j] ? 1 : 0;
        cnon += nb[j] ? 1 : 0;
    }

    int ss = cstart, sn = cnon;
#pragma unroll
    for (int o = 1; o < 64; o <<= 1) {
        int us = __shfl_up(ss, o);
        int un = __shfl_up(sn, o);
        if (lane >= o) { ss += us; sn += un; }
    }
    if (lane == 63) { wtot_s[wv] = ss; wtot_n[wv] = sn; }
    __syncthreads();

    int bs = 0, bn = 0, tot_s = 0, tot_n = 0;
#pragma unroll
    for (int j = 0; j < 16; ++j) {
        int a = wtot_s[j], c = wtot_n[j];
        if (j < wv) { bs += a; bn += c; }
        tot_s += a; tot_n += c;
    }
    bs += ss - cstart;  // exclusive prefix
    bn += sn - cnon;

#pragma unroll
    for (int j = 0; j < TPT; ++j) {
        if (st[j]) { segs[bs] = t0 + j; pvals[bs] = bn; bs++; }
        bn += nb[j] ? 1 : 0;
    }
    __syncthreads();

    int ns = tot_s;
    for (int w = tid; w < TT; w += 1024) {
        int c = 0;
        if (w < ns) {
            int pe = (w + 1 < ns) ? pvals[w + 1] : tot_n;
            c = pe - pvals[w];
            seg_start[b * TT + w] = segs[w];
        }
        counts[b * TT + w] = c;
        mask_out[b * TT + w] = (w < ns) ? 1.0f : 0.0f;
    }
    if (tid == 0) nseg_g[b] = ns;
}

// ---------------------------------------------------------------------------
// Fused pool -> GEMM -> LN -> store.
// LEADER-BLOCK structure: real tiles at wbase%32==0 process 32 rows
// (non-leader real tiles return; fill tiles write 8 rows as before).
// Why: R0 streamed the full 256KB Wt from L2 per 8-row block (458MB L2
// traffic; ~64 B/cyc/CU demand > ~56 B/cyc/CU L2 feed -> GEMM ran at
// Wt-stream speed 1792 times). Leaders amortize the stream 4x (each Wt
// register feeds 128 FMAs) and, having the lowest y indices, dispatch FIRST
// and run long while the 14.5K fill blocks stream constant writes
// concurrently -- overlapping the two phases instead of interleaving 1792
// latency-exposed pool->barrier->GEMM slices.
__global__ __launch_bounds__(256) void fused_kernel(
    const float* __restrict__ x, const float* __restrict__ Wt,
    const float* __restrict__ bp, const float* __restrict__ gamma,
    const float* __restrict__ beta, const int* __restrict__ counts,
    const int* __restrict__ seg_start, const int* __restrict__ nseg,
    const float* __restrict__ ln_e, float* __restrict__ out) {
    __shared__ float pooled[LROWS][DD];   // 32 KB
    __shared__ float red[LROWS][4][2];    // 1 KB

    int b = blockIdx.x;
    int wbase = blockIdx.y * RPB;
    int ns = nseg[b];
    int tid = threadIdx.x;
    int lane = tid & 63;
    int wv = tid >> 6;

    if (wbase >= ns) {  // pure fill tile: 8 rows of LN(b_proj)
        size_t rowbase = ((size_t)(b * TT + wbase)) * DD;
        vfloat4 lv = *(const vfloat4*)(ln_e + 4 * lane);
        float* o = out + rowbase + 4 * lane;
#pragma unroll
        for (int rr = 0; rr < 2; ++rr) {
            int row = wv * 2 + rr;
            __builtin_nontemporal_store(lv, (vfloat4*)(o + (size_t)row * DD));
        }
        return;
    }
    if (wbase & (LROWS - 1)) return;  // non-leader real tile: handled by leader
    // ---- leader: rows [wbase, wbase+32). Rows >= ns get pooled=0 -> acc=bias
    // -> exactly LN(b_proj); overlapping fill tiles write the same values.
    int nr = min(LROWS, ns - wbase);

    // ---- pooling: wave owns rows [wv*8, wv*8+8), processed in pairs so 16
    // independent loads (2 rows x 8 accumulators) are in flight (R0 pattern).
#pragma unroll 1
    for (int pr = 0; pr < 4; ++pr) {
#pragma unroll
        for (int rr = 0; rr < 2; ++rr) {
            int row = wv * 8 + pr * 2 + rr;
            vfloat4 r = {0.f, 0.f, 0.f, 0.f};
            if (row < nr) {
                int w = wbase + row;
                int s = seg_start[b * TT + w];
                int len = counts[b * TT + w];
                const vfloat4* xp =
                    (const vfloat4*)(x + ((size_t)(b * TT + s)) * DD) + lane;
                vfloat4 a[8];
#pragma unroll
                for (int j = 0; j < 8; ++j) a[j] = (vfloat4){0.f, 0.f, 0.f, 0.f};
                int t = 0;
                for (; t + 8 <= len; t += 8) {
#pragma unroll
                    for (int j = 0; j < 8; ++j)
                        a[j] += __builtin_nontemporal_load(xp + (t + j) * 64);
                }
                // tail: up to 7 loads, wave-uniform predicates, independent
#pragma unroll
                for (int j = 0; j < 7; ++j)
                    if (t + j < len)
                        a[j] += __builtin_nontemporal_load(xp + (t + j) * 64);
                r = ((a[0] + a[1]) + (a[2] + a[3])) +
                    ((a[4] + a[5]) + (a[6] + a[7]));
                r *= (1.f / (float)len);
            }
            *(vfloat4*)&pooled[row][lane * 4] = r;
        }
    }

    // ---- GEMM setup: issue first Wt prefetch BEFORE the barrier (independent
    // of pooled; R0's proven 1-step depth -- deeper cost VGPRs, round 4).
    int c = tid;  // output column 0..255
    const float* Wc = Wt + c;
    float w0 = Wc[0 * DD];
    float w1 = Wc[1 * DD];
    float w2 = Wc[2 * DD];
    float w3 = Wc[3 * DD];
    float bias = bp[c];

    __syncthreads();

    // ---- GEMM: acc[r] = bp[c] + sum_d pooled[r][d] * Wt[d][c]
    float acc[LROWS];
#pragma unroll
    for (int r = 0; r < LROWS; ++r) acc[r] = bias;

#pragma unroll 1
    for (int d0 = 0; d0 < DD; d0 += 4) {
        int dn = (d0 + 4) & 255;  // wraps harmlessly on last iter
        float n0 = Wc[(dn + 0) * DD];
        float n1 = Wc[(dn + 1) * DD];
        float n2 = Wc[(dn + 2) * DD];
        float n3 = Wc[(dn + 3) * DD];
#pragma unroll
        for (int r = 0; r < LROWS; ++r) {
            const float4 p = *(const float4*)&pooled[r][d0];  // broadcast
            acc[r] = fmaf(p.x, w0, acc[r]);
            acc[r] = fmaf(p.y, w1, acc[r]);
            acc[r] = fmaf(p.z, w2, acc[r]);
            acc[r] = fmaf(p.w, w3, acc[r]);
        }
        w0 = n0; w1 = n1; w2 = n2; w3 = n3;
    }

    // ---- LN: wave-partials over 64 cols, combined across 4 waves via LDS.
#pragma unroll
    for (int r = 0; r < LROWS; ++r) {
        float s = acc[r];
        float sq = acc[r] * acc[r];
#pragma unroll
        for (int o = 32; o > 0; o >>= 1) {
            s += __shfl_down(s, o);
            sq += __shfl_down(sq, o);
        }
        if (lane == 0) { red[r][wv][0] = s; red[r][wv][1] = sq; }
    }
    __syncthreads();

    float ga = gamma[c], be = beta[c];
    size_t rowbase = ((size_t)(b * TT + wbase)) * DD;
#pragma unroll
    for (int r = 0; r < LROWS; ++r) {
        float4 q0 = *(const float4*)&red[r][0][0];  // wv0.s, wv0.sq, wv1.s, wv1.sq
        float4 q1 = *(const float4*)&red[r][2][0];  // wv2.s, wv2.sq, wv3.s, wv3.sq
        float s = (q0.x + q0.z) + (q1.x + q1.z);
        float sq = (q0.y + q0.w) + (q1.y + q1.w);
        float mu = s * (1.f / (float)DD);
        float var = sq * (1.f / (float)DD) - mu * mu;
        float rs = rsqrtf(fmaxf(var, 0.f) + LN_EPS);
        float v = (acc[r] - mu) * rs * ga + be;
        __builtin_nontemporal_store(v, out + rowbase + (size_t)r * DD + c);
    }
}

// ---------------------------------------------------------------------------
extern "C" void kernel_launch(void* const* d_in, const int* in_sizes, int n_in,
                              void* d_out, int out_size, void* d_ws, size_t ws_size,
                              hipStream_t stream) {
    const float* x = (const float*)d_in[0];
    const int* ids = (const int*)d_in[1];
    const float* W = (const float*)d_in[2];
    const float* bp = (const float*)d_in[3];
    const float* gamma = (const float*)d_in[4];
    const float* beta = (const float*)d_in[5];

    float* out = (float*)d_out;                       // [B, T, D]
    float* mask = out + (size_t)BB * TT * DD;         // [B, T]

    // workspace layout
    char* ws = (char*)d_ws;
    int* counts = (int*)ws;                                    // B*T ints
    int* seg_start = (int*)(ws + (size_t)BB * TT * 4);         // B*T ints
    int* nseg = (int*)(ws + (size_t)2 * BB * TT * 4);          // B ints
    float* Wt = (float*)(ws + (size_t)2 * BB * TT * 4 + 256);  // D*D floats
    float* ln_e = Wt + DD * DD;                                // D floats

    hipLaunchKernelGGL(setup_kernel, dim3(BB + 64 + 1), dim3(1024), 0, stream,
                       ids, W, bp, gamma, beta, counts, seg_start, nseg, mask,
                       Wt, ln_e);
    hipLaunchKernelGGL(fused_kernel, dim3(BB, TT / RPB), dim3(256), 0, stream,
                       x, Wt, bp, gamma, beta, counts, seg_start, nseg, ln_e, out);
}

// Round 6
// 296.951 us; speedup vs baseline: 1.1227x; 1.1227x over previous
//
#include <hip/hip_runtime.h>
#include <hip/hip_bf16.h>
#include <math.h>

// Problem constants (fixed by setup_inputs)
#define BB 16
#define TT 8192
#define DD 256
#define MAXSEG 4096   // max possible segments per row (alternating pattern)
#define RPB 8         // segment rows per block
#define LN_EPS 1e-5f

typedef float vfloat4 __attribute__((ext_vector_type(4)));  // nontemporal-safe

// readlane: wave-uniform broadcast through the SCALAR register file --
// bypasses the LDS pipe (a ds_read_b128 broadcast still delivers 64x16B
// = 1KB per instruction at ~85B/cyc; that pipe was the real-block phase
// limiter: 28 waves x 512 b128 x ~12cyc = ~72us/CU).
__device__ __forceinline__ float rl(float v, int l) {
    return __uint_as_float(__builtin_amdgcn_readlane(__float_as_uint(v), l));
}

// ---------------------------------------------------------------------------
// Setup kernel (merged): blocks [0,BB) run the per-batch-row segment scan;
// blocks [BB, BB+64) transpose W (4 rows each); block BB+64 computes
// LN(b_proj) with a single wave. 1024 threads each.
__global__ __launch_bounds__(1024) void setup_kernel(
    const int* __restrict__ ids, const float* __restrict__ W,
    const float* __restrict__ bp, const float* __restrict__ gamma,
    const float* __restrict__ beta, int* __restrict__ counts,
    int* __restrict__ seg_start, int* __restrict__ nseg_g,
    float* __restrict__ mask_out, float* __restrict__ Wt,
    float* __restrict__ ln_empty) {
    __shared__ int wtot_s[16];
    __shared__ int wtot_n[16];
    __shared__ int segs[MAXSEG];
    __shared__ int pvals[MAXSEG];

    int tid = threadIdx.x;
    int lane = tid & 63;
    int wv = tid >> 6;

    if (blockIdx.x >= BB) {
        int bi = blockIdx.x - BB;
        if (bi < 64) {  // transpose: 4 d-rows per block
            int d = bi * 4 + (tid >> 8);
            int e = tid & 255;
            Wt[d * DD + e] = W[e * DD + d];
        } else if (wv == 0) {  // LN of b_proj, one wave
            int e0 = lane * 4;
            float4 v = *(const float4*)(bp + e0);
            float s = v.x + v.y + v.z + v.w;
            float sq = v.x * v.x + v.y * v.y + v.z * v.z + v.w * v.w;
#pragma unroll
            for (int o = 32; o > 0; o >>= 1) {
                s += __shfl_down(s, o);
                sq += __shfl_down(sq, o);
            }
            s = __shfl(s, 0);
            sq = __shfl(sq, 0);
            float mu = s * (1.f / (float)DD);
            float var = sq * (1.f / (float)DD) - mu * mu;
            float rs = rsqrtf(fmaxf(var, 0.f) + LN_EPS);
            float4 ge = *(const float4*)(gamma + e0);
            float4 be = *(const float4*)(beta + e0);
            float4 o4;
            o4.x = (v.x - mu) * rs * ge.x + be.x;
            o4.y = (v.y - mu) * rs * ge.y + be.y;
            o4.z = (v.z - mu) * rs * ge.z + be.z;
            o4.w = (v.w - mu) * rs * ge.w + be.w;
            *(float4*)(ln_empty + e0) = o4;
        }
        return;
    }

    // ---- segment scan, one block per batch row
    const int TPT = 8;  // tokens per thread
    int b = blockIdx.x;
    const int* row = ids + b * TT;
    int t0 = tid * TPT;

    int4 q0 = ((const int4*)(row + t0))[0];
    int4 q1 = ((const int4*)(row + t0))[1];
    int v[TPT] = {q0.x, q0.y, q0.z, q0.w, q1.x, q1.y, q1.z, q1.w};
    int prev = (tid == 0) ? 0 : row[t0 - 1];  // 0 == boundary

    bool nb[TPT], st[TPT];
    int cstart = 0, cnon = 0;
#pragma unroll
    for (int j = 0; j < TPT; ++j) {
        nb[j] = (v[j] != 0);
        int pv = (j == 0) ? prev : v[j - 1];
        st[j] = nb[j] && (pv == 0);
        cstart += st[j] ? 1 : 0;
        cnon += nb[j] ? 1 : 0;
    }

    int ss = cstart, sn = cnon;
#pragma unroll
    for (int o = 1; o < 64; o <<= 1) {
        int us = __shfl_up(ss, o);
        int un = __shfl_up(sn, o);
        if (lane >= o) { ss += us; sn += un; }
    }
    if (lane == 63) { wtot_s[wv] = ss; wtot_n[wv] = sn; }
    __syncthreads();

    int bs = 0, bn = 0, tot_s = 0, tot_n = 0;
#pragma unroll
    for (int j = 0; j < 16; ++j) {
        int a = wtot_s[j], c = wtot_n[j];
        if (j < wv) { bs += a; bn += c; }
        tot_s += a; tot_n += c;
    }
    bs += ss - cstart;  // exclusive prefix
    bn += sn - cnon;

#pragma unroll
    for (int j = 0; j < TPT; ++j) {
        if (st[j]) { segs[bs] = t0 + j; pvals[bs] = bn; bs++; }
        bn += nb[j] ? 1 : 0;
    }
    __syncthreads();

    int ns = tot_s;
    for (int w = tid; w < TT; w += 1024) {
        int c = 0;
        if (w < ns) {
            int pe = (w + 1 < ns) ? pvals[w + 1] : tot_n;
            c = pe - pvals[w];
            seg_start[b * TT + w] = segs[w];
        }
        counts[b * TT + w] = c;
        mask_out[b * TT + w] = (w < ns) ? 1.0f : 0.0f;
    }
    if (tid == 0) nseg_g[b] = ns;
}

// ---------------------------------------------------------------------------
// Fused pool -> GEMM -> LN -> store (R0 structure; only the GEMM operand
// delivery changed). After the barrier, each lane loads pooled[r][4l..4l+3]
// (8 ds_read_b128 per wave TOTAL, A register-resident in 32 VGPRs). The
// K-loop then broadcasts A via v_readlane into SGPRs (uniform loop counter
// as lane index) and runs v_fma(v,s,v). DS instructions per wave: 512 -> 8.
// FMA order over d is identical to R0 -> bit-identical output.
__global__ __launch_bounds__(256) void fused_kernel(
    const float* __restrict__ x, const float* __restrict__ Wt,
    const float* __restrict__ bp, const float* __restrict__ gamma,
    const float* __restrict__ beta, const int* __restrict__ counts,
    const int* __restrict__ seg_start, const int* __restrict__ nseg,
    const float* __restrict__ ln_e, float* __restrict__ out) {
    __shared__ float pooled[RPB][DD];   // 8 KB
    __shared__ float red[4][RPB][2];

    int b = blockIdx.x;
    int wbase = blockIdx.y * RPB;
    int ns = nseg[b];
    int tid = threadIdx.x;
    int lane = tid & 63;
    int wv = tid >> 6;
    size_t rowbase = ((size_t)(b * TT + wbase)) * DD;

    if (wbase >= ns) {  // pure fill tile: 8 rows of LN(b_proj)
        vfloat4 lv = *(const vfloat4*)(ln_e + 4 * lane);
        float* o = out + rowbase + 4 * lane;
#pragma unroll
        for (int rr = 0; rr < 2; ++rr) {
            int row = wv * 2 + rr;
            __builtin_nontemporal_store(lv, (vfloat4*)(o + (size_t)row * DD));
        }
        return;
    }
    int nr = min(RPB, ns - wbase);

    // ---- pooling: 2 rows per wave; all loads independent (8 accumulators)
#pragma unroll
    for (int rr = 0; rr < 2; ++rr) {
        int row = wv * 2 + rr;
        vfloat4 r = {0.f, 0.f, 0.f, 0.f};
        if (row < nr) {
            int w = wbase + row;
            int s = seg_start[b * TT + w];
            int len = counts[b * TT + w];
            const vfloat4* xp =
                (const vfloat4*)(x + ((size_t)(b * TT + s)) * DD) + lane;
            vfloat4 a[8];
#pragma unroll
            for (int j = 0; j < 8; ++j) a[j] = (vfloat4){0.f, 0.f, 0.f, 0.f};
            int t = 0;
            for (; t + 8 <= len; t += 8) {
#pragma unroll
                for (int j = 0; j < 8; ++j)
                    a[j] += __builtin_nontemporal_load(xp + (t + j) * 64);
            }
            // tail: up to 7 loads, wave-uniform predicates, independent accs
#pragma unroll
            for (int j = 0; j < 7; ++j)
                if (t + j < len)
                    a[j] += __builtin_nontemporal_load(xp + (t + j) * 64);
            r = ((a[0] + a[1]) + (a[2] + a[3])) + ((a[4] + a[5]) + (a[6] + a[7]));
            r *= (1.f / (float)len);
        }
        *(vfloat4*)&pooled[row][lane * 4] = r;
    }
    __syncthreads();

    // ---- A into registers: lane l holds pooled[r][4l..4l+3] for all 8 rows
    vfloat4 vr[RPB];
#pragma unroll
    for (int r = 0; r < RPB; ++r)
        vr[r] = *(const vfloat4*)&pooled[r][lane * 4];

    // ---- GEMM: acc[r] = bp[c] + sum_d pooled[r][d] * Wt[d][c]
    int c = tid;  // output column 0..255 (wv*64+lane)
    const float* Wc = Wt + c;
    float bias = bp[c];
    float acc[RPB];
#pragma unroll
    for (int r = 0; r < RPB; ++r) acc[r] = bias;

    float w0 = Wc[0 * DD];
    float w1 = Wc[1 * DD];
    float w2 = Wc[2 * DD];
    float w3 = Wc[3 * DD];
#pragma unroll 1
    for (int i = 0; i < 64; ++i) {  // d = 4i..4i+3
        int dn = ((i + 1) & 63) * 4;  // wraps harmlessly on last iter
        float n0 = Wc[(dn + 0) * DD];
        float n1 = Wc[(dn + 1) * DD];
        float n2 = Wc[(dn + 2) * DD];
        float n3 = Wc[(dn + 3) * DD];
#pragma unroll
        for (int r = 0; r < RPB; ++r) {
            acc[r] = fmaf(rl(vr[r].x, i), w0, acc[r]);
            acc[r] = fmaf(rl(vr[r].y, i), w1, acc[r]);
            acc[r] = fmaf(rl(vr[r].z, i), w2, acc[r]);
            acc[r] = fmaf(rl(vr[r].w, i), w3, acc[r]);
        }
        w0 = n0; w1 = n1; w2 = n2; w3 = n3;
    }

    // ---- LN: wave-partials over 64 cols, combined across 4 waves via LDS.
    // Padding rows (pooled==0 -> acc==bias) produce exactly LN(b_proj).
#pragma unroll
    for (int r = 0; r < RPB; ++r) {
        float s = acc[r];
        float sq = acc[r] * acc[r];
#pragma unroll
        for (int o = 32; o > 0; o >>= 1) {
            s += __shfl_down(s, o);
            sq += __shfl_down(sq, o);
        }
        if (lane == 0) { red[wv][r][0] = s; red[wv][r][1] = sq; }
    }
    __syncthreads();

    float ga = gamma[c], be = beta[c];
#pragma unroll
    for (int r = 0; r < RPB; ++r) {
        float s = red[0][r][0] + red[1][r][0] + red[2][r][0] + red[3][r][0];
        float sq = red[0][r][1] + red[1][r][1] + red[2][r][1] + red[3][r][1];
        float mu = s * (1.f / (float)DD);
        float var = sq * (1.f / (float)DD) - mu * mu;
        float rs = rsqrtf(fmaxf(var, 0.f) + LN_EPS);
        float v = (acc[r] - mu) * rs * ga + be;
        __builtin_nontemporal_store(v, out + rowbase + (size_t)r * DD + c);
    }
}

// ---------------------------------------------------------------------------
extern "C" void kernel_launch(void* const* d_in, const int* in_sizes, int n_in,
                              void* d_out, int out_size, void* d_ws, size_t ws_size,
                              hipStream_t stream) {
    const float* x = (const float*)d_in[0];
    const int* ids = (const int*)d_in[1];
    const float* W = (const float*)d_in[2];
    const float* bp = (const float*)d_in[3];
    const float* gamma = (const float*)d_in[4];
    const float* beta = (const float*)d_in[5];

    float* out = (float*)d_out;                       // [B, T, D]
    float* mask = out + (size_t)BB * TT * DD;         // [B, T]

    // workspace layout
    char* ws = (char*)d_ws;
    int* counts = (int*)ws;                                    // B*T ints
    int* seg_start = (int*)(ws + (size_t)BB * TT * 4);         // B*T ints
    int* nseg = (int*)(ws + (size_t)2 * BB * TT * 4);          // B ints
    float* Wt = (float*)(ws + (size_t)2 * BB * TT * 4 + 256);  // D*D floats
    float* ln_e = Wt + DD * DD;                                // D floats

    hipLaunchKernelGGL(setup_kernel, dim3(BB + 64 + 1), dim3(1024), 0, stream,
                       ids, W, bp, gamma, beta, counts, seg_start, nseg, mask,
                       Wt, ln_e);
    hipLaunchKernelGGL(fused_kernel, dim3(BB, TT / RPB), dim3(256), 0, stream,
                       x, Wt, bp, gamma, beta, counts, seg_start, nseg, ln_e, out);
}

// Round 7
// 279.370 us; speedup vs baseline: 1.1933x; 1.0629x over previous
//
#include <hip/hip_runtime.h>
#include <hip/hip_bf16.h>
#include <math.h>

// Problem constants (fixed by setup_inputs)
#define BB 16
#define TT 8192
#define DD 256
#define MAXSEG 4096   // max possible segments per row (alternating pattern)
#define RPB 8         // segment rows per block
#define LN_EPS 1e-5f
#define FILL_BLOCKS 2048

typedef float vfloat4 __attribute__((ext_vector_type(4)));  // nontemporal-safe

// ---------------------------------------------------------------------------
// Setup kernel (merged): blocks [0,BB) run the per-batch-row segment scan;
// blocks [BB, BB+64) transpose W (4 rows each); block BB+64 computes
// LN(b_proj) with a single wave. 1024 threads each.
__global__ __launch_bounds__(1024) void setup_kernel(
    const int* __restrict__ ids, const float* __restrict__ W,
    const float* __restrict__ bp, const float* __restrict__ gamma,
    const float* __restrict__ beta, int* __restrict__ counts,
    int* __restrict__ seg_start, int* __restrict__ nseg_g,
    float* __restrict__ mask_out, float* __restrict__ Wt,
    float* __restrict__ ln_empty) {
    __shared__ int wtot_s[16];
    __shared__ int wtot_n[16];
    __shared__ int segs[MAXSEG];
    __shared__ int pvals[MAXSEG];

    int tid = threadIdx.x;
    int lane = tid & 63;
    int wv = tid >> 6;

    if (blockIdx.x >= BB) {
        int bi = blockIdx.x - BB;
        if (bi < 64) {  // transpose: 4 d-rows per block
            int d = bi * 4 + (tid >> 8);
            int e = tid & 255;
            Wt[d * DD + e] = W[e * DD + d];
        } else if (wv == 0) {  // LN of b_proj, one wave
            int e0 = lane * 4;
            float4 v = *(const float4*)(bp + e0);
            float s = v.x + v.y + v.z + v.w;
            float sq = v.x * v.x + v.y * v.y + v.z * v.z + v.w * v.w;
#pragma unroll
            for (int o = 32; o > 0; o >>= 1) {
                s += __shfl_down(s, o);
                sq += __shfl_down(sq, o);
            }
            s = __shfl(s, 0);
            sq = __shfl(sq, 0);
            float mu = s * (1.f / (float)DD);
            float var = sq * (1.f / (float)DD) - mu * mu;
            float rs = rsqrtf(fmaxf(var, 0.f) + LN_EPS);
            float4 ge = *(const float4*)(gamma + e0);
            float4 be = *(const float4*)(beta + e0);
            float4 o4;
            o4.x = (v.x - mu) * rs * ge.x + be.x;
            o4.y = (v.y - mu) * rs * ge.y + be.y;
            o4.z = (v.z - mu) * rs * ge.z + be.z;
            o4.w = (v.w - mu) * rs * ge.w + be.w;
            *(float4*)(ln_empty + e0) = o4;
        }
        return;
    }

    // ---- segment scan, one block per batch row
    const int TPT = 8;  // tokens per thread
    int b = blockIdx.x;
    const int* row = ids + b * TT;
    int t0 = tid * TPT;

    int4 q0 = ((const int4*)(row + t0))[0];
    int4 q1 = ((const int4*)(row + t0))[1];
    int v[TPT] = {q0.x, q0.y, q0.z, q0.w, q1.x, q1.y, q1.z, q1.w};
    int prev = (tid == 0) ? 0 : row[t0 - 1];  // 0 == boundary

    bool nb[TPT], st[TPT];
    int cstart = 0, cnon = 0;
#pragma unroll
    for (int j = 0; j < TPT; ++j) {
        nb[j] = (v[j] != 0);
        int pv = (j == 0) ? prev : v[j - 1];
        st[j] = nb[j] && (pv == 0);
        cstart += st[j] ? 1 : 0;
        cnon += nb[j] ? 1 : 0;
    }

    int ss = cstart, sn = cnon;
#pragma unroll
    for (int o = 1; o < 64; o <<= 1) {
        int us = __shfl_up(ss, o);
        int un = __shfl_up(sn, o);
        if (lane >= o) { ss += us; sn += un; }
    }
    if (lane == 63) { wtot_s[wv] = ss; wtot_n[wv] = sn; }
    __syncthreads();

    int bs = 0, bn = 0, tot_s = 0, tot_n = 0;
#pragma unroll
    for (int j = 0; j < 16; ++j) {
        int a = wtot_s[j], c = wtot_n[j];
        if (j < wv) { bs += a; bn += c; }
        tot_s += a; tot_n += c;
    }
    bs += ss - cstart;  // exclusive prefix
    bn += sn - cnon;

#pragma unroll
    for (int j = 0; j < TPT; ++j) {
        if (st[j]) { segs[bs] = t0 + j; pvals[bs] = bn; bs++; }
        bn += nb[j] ? 1 : 0;
    }
    __syncthreads();

    int ns = tot_s;
    for (int w = tid; w < TT; w += 1024) {
        int c = 0;
        if (w < ns) {
            int pe = (w + 1 < ns) ? pvals[w + 1] : tot_n;
            c = pe - pvals[w];
            seg_start[b * TT + w] = segs[w];
        }
        counts[b * TT + w] = c;
        mask_out[b * TT + w] = (w < ns) ? 1.0f : 0.0f;
    }
    if (tid == 0) nseg_g[b] = ns;
}

// ---------------------------------------------------------------------------
// Real-tile kernel: pool -> GEMM -> LN -> store, R0 body verbatim. Only
// tiles with wbase < ns do work (straddle tile's padding rows get pooled=0
// -> acc=bias -> exactly LN(b_proj)). Grid y limited to MAXSEG/RPB=512
// since ns <= 4096 structurally.
__global__ __launch_bounds__(256) void real_kernel(
    const float* __restrict__ x, const float* __restrict__ Wt,
    const float* __restrict__ bp, const float* __restrict__ gamma,
    const float* __restrict__ beta, const int* __restrict__ counts,
    const int* __restrict__ seg_start, const int* __restrict__ nseg,
    float* __restrict__ out) {
    __shared__ float pooled[RPB][DD];   // 8 KB
    __shared__ float red[4][RPB][2];

    int b = blockIdx.x;
    int wbase = blockIdx.y * RPB;
    int ns = nseg[b];
    if (wbase >= ns) return;  // handled by fill_kernel
    int tid = threadIdx.x;
    int lane = tid & 63;
    int wv = tid >> 6;
    size_t rowbase = ((size_t)(b * TT + wbase)) * DD;
    int nr = min(RPB, ns - wbase);

    // ---- pooling: 2 rows per wave; all loads independent (8 accumulators)
#pragma unroll
    for (int rr = 0; rr < 2; ++rr) {
        int row = wv * 2 + rr;
        vfloat4 r = {0.f, 0.f, 0.f, 0.f};
        if (row < nr) {
            int w = wbase + row;
            int s = seg_start[b * TT + w];
            int len = counts[b * TT + w];
            const vfloat4* xp =
                (const vfloat4*)(x + ((size_t)(b * TT + s)) * DD) + lane;
            vfloat4 a[8];
#pragma unroll
            for (int j = 0; j < 8; ++j) a[j] = (vfloat4){0.f, 0.f, 0.f, 0.f};
            int t = 0;
            for (; t + 8 <= len; t += 8) {
#pragma unroll
                for (int j = 0; j < 8; ++j)
                    a[j] += __builtin_nontemporal_load(xp + (t + j) * 64);
            }
            // tail: up to 7 loads, wave-uniform predicates, independent accs
#pragma unroll
            for (int j = 0; j < 7; ++j)
                if (t + j < len)
                    a[j] += __builtin_nontemporal_load(xp + (t + j) * 64);
            r = ((a[0] + a[1]) + (a[2] + a[3])) + ((a[4] + a[5]) + (a[6] + a[7]));
            r *= (1.f / (float)len);
        }
        *(vfloat4*)&pooled[row][lane * 4] = r;
    }
    __syncthreads();

    // ---- GEMM: acc[r] = bp[c] + sum_d pooled[r][d] * Wt[d][c]
    int c = tid;  // output column 0..255
    float acc[RPB];
    float bias = bp[c];
#pragma unroll
    for (int r = 0; r < RPB; ++r) acc[r] = bias;

    const float* Wc = Wt + c;
    float w0 = Wc[0 * DD];
    float w1 = Wc[1 * DD];
    float w2 = Wc[2 * DD];
    float w3 = Wc[3 * DD];
#pragma unroll 1
    for (int d0 = 0; d0 < DD; d0 += 4) {
        int dn = (d0 + 4) & 255;  // wraps harmlessly on last iter
        float n0 = Wc[(dn + 0) * DD];
        float n1 = Wc[(dn + 1) * DD];
        float n2 = Wc[(dn + 2) * DD];
        float n3 = Wc[(dn + 3) * DD];
#pragma unroll
        for (int r = 0; r < RPB; ++r) {
            const float4 p = *(const float4*)&pooled[r][d0];  // broadcast
            acc[r] = fmaf(p.x, w0, acc[r]);
            acc[r] = fmaf(p.y, w1, acc[r]);
            acc[r] = fmaf(p.z, w2, acc[r]);
            acc[r] = fmaf(p.w, w3, acc[r]);
        }
        w0 = n0; w1 = n1; w2 = n2; w3 = n3;
    }

    // ---- LN: wave-partials over 64 cols, combined across 4 waves via LDS.
#pragma unroll
    for (int r = 0; r < RPB; ++r) {
        float s = acc[r];
        float sq = acc[r] * acc[r];
#pragma unroll
        for (int o = 32; o > 0; o >>= 1) {
            s += __shfl_down(s, o);
            sq += __shfl_down(sq, o);
        }
        if (lane == 0) { red[wv][r][0] = s; red[wv][r][1] = sq; }
    }
    __syncthreads();

    float ga = gamma[c], be = beta[c];
#pragma unroll
    for (int r = 0; r < RPB; ++r) {
        float s = red[0][r][0] + red[1][r][0] + red[2][r][0] + red[3][r][0];
        float sq = red[0][r][1] + red[1][r][1] + red[2][r][1] + red[3][r][1];
        float mu = s * (1.f / (float)DD);
        float var = sq * (1.f / (float)DD) - mu * mu;
        float rs = rsqrtf(fmaxf(var, 0.f) + LN_EPS);
        float v = (acc[r] - mu) * rs * ga + be;
        __builtin_nontemporal_store(v, out + rowbase + (size_t)r * DD + c);
    }
}

// ---------------------------------------------------------------------------
// Fill kernel: rows [ceil8(ns), TT) of every batch get the constant
// LN(b_proj) row. Zero LDS, tiny VGPR count -> max occupancy; grid-stride
// over tiles; pure nontemporal write stream (114 MB) at write roofline.
__global__ __launch_bounds__(256) void fill_kernel(
    const int* __restrict__ nseg, const float* __restrict__ ln_e,
    float* __restrict__ out) {
    int tid = threadIdx.x;
    int lane = tid & 63;
    int wv = tid >> 6;
    vfloat4 lv = *(const vfloat4*)(ln_e + 4 * lane);

    const int NT = BB * (TT / RPB);
    for (int t = blockIdx.x; t < NT; t += FILL_BLOCKS) {
        int b = t & (BB - 1);
        int wbase = (t >> 4) * RPB;
        if (wbase < nseg[b]) continue;  // real tile: written by real_kernel
        float* o = out + ((size_t)(b * TT + wbase)) * DD + 4 * lane;
#pragma unroll
        for (int rr = 0; rr < 2; ++rr) {
            int row = wv * 2 + rr;
            __builtin_nontemporal_store(lv, (vfloat4*)(o + (size_t)row * DD));
        }
    }
}

// ---------------------------------------------------------------------------
extern "C" void kernel_launch(void* const* d_in, const int* in_sizes, int n_in,
                              void* d_out, int out_size, void* d_ws, size_t ws_size,
                              hipStream_t stream) {
    const float* x = (const float*)d_in[0];
    const int* ids = (const int*)d_in[1];
    const float* W = (const float*)d_in[2];
    const float* bp = (const float*)d_in[3];
    const float* gamma = (const float*)d_in[4];
    const float* beta = (const float*)d_in[5];

    float* out = (float*)d_out;                       // [B, T, D]
    float* mask = out + (size_t)BB * TT * DD;         // [B, T]

    // workspace layout
    char* ws = (char*)d_ws;
    int* counts = (int*)ws;                                    // B*T ints
    int* seg_start = (int*)(ws + (size_t)BB * TT * 4);         // B*T ints
    int* nseg = (int*)(ws + (size_t)2 * BB * TT * 4);          // B ints
    float* Wt = (float*)(ws + (size_t)2 * BB * TT * 4 + 256);  // D*D floats
    float* ln_e = Wt + DD * DD;                                // D floats

    hipLaunchKernelGGL(setup_kernel, dim3(BB + 64 + 1), dim3(1024), 0, stream,
                       ids, W, bp, gamma, beta, counts, seg_start, nseg, mask,
                       Wt, ln_e);
    hipLaunchKernelGGL(real_kernel, dim3(BB, MAXSEG / RPB), dim3(256), 0,
                       stream, x, Wt, bp, gamma, beta, counts, seg_start, nseg,
                       out);
    hipLaunchKernelGGL(fill_kernel, dim3(FILL_BLOCKS), dim3(256), 0, stream,
                       nseg, ln_e, out);
}